// Round 2
// baseline (25215.802 us; speedup 1.0000x reference)
//
#include <hip/hip_runtime.h>
#include <hip/hip_bf16.h>

typedef unsigned short ushort_t;
typedef __attribute__((ext_vector_type(8))) short bf16x8;
typedef __attribute__((ext_vector_type(4))) float f32x4;

#define T_DIM 128
#define B_DIM 512
#define DIN 512
#define H_DIM 512
#define DM 256
#define HYP 256
#define L_DIM 100

__device__ __forceinline__ float bf2f(ushort_t u) {
    return __uint_as_float(((unsigned)u) << 16);
}
__device__ __forceinline__ ushort_t f2bf(float f) {
    unsigned u = __float_as_uint(f);
    unsigned r = (u + 0x7fffu + ((u >> 16) & 1u)) >> 16;
    return (ushort_t)r;
}
__device__ __forceinline__ float sigmoidf_(float x) {
    return 1.0f / (1.0f + __expf(-x));
}
// NaN/inf scrub + clamp: keeps garbage-world values finite so failures are diagnosable.
__device__ __forceinline__ float fixf(float v) {
    if (!(v == v)) return 0.f;
    return fminf(fmaxf(v, -65504.f), 65504.f);
}
__device__ __forceinline__ bf16x8 zero8() {
    bf16x8 z = {0, 0, 0, 0, 0, 0, 0, 0};
    return z;
}

// ---------------------------------------------------------------------------
// dtype detector: valid bf16 never has exponent 0xFF; f32 read as ushorts does
// (~0.4% of low halves). Single block -> flag: 1 = inputs are f32, 0 = bf16.
// ---------------------------------------------------------------------------
__global__ __launch_bounds__(256) void detect_kernel(const ushort_t* x, int nscan, int* flag) {
    __shared__ int found;
    if (threadIdx.x == 0) found = 0;
    __syncthreads();
    int f = 0;
    for (int i = threadIdx.x; i < nscan; i += 256) {
        unsigned u = x[i];
        if ((u & 0x7F80u) == 0x7F80u) f = 1;
    }
    if (f) atomicOr(&found, 1);
    __syncthreads();
    if (threadIdx.x == 0) *flag = found;
}

// ---------------------------------------------------------------------------
// Ingest: convert all 21 float tensors to canonical bf16 copies in workspace.
// ---------------------------------------------------------------------------
struct IngestP {
    const void* src[21];
    ushort_t* dst[21];
    int n[21];
    long total;
    const int* flag;
};

__global__ __launch_bounds__(256) void ingest_all(IngestP p) {
    int f = *p.flag;
    long idx0 = (long)blockIdx.x * 256 + threadIdx.x;
    long stride = (long)gridDim.x * 256;
    for (long idx = idx0; idx < p.total; idx += stride) {
        long r = idx;
#pragma unroll 1
        for (int t = 0; t < 21; t++) {
            if (r < p.n[t]) {
                p.dst[t][r] = f ? f2bf(((const float*)p.src[t])[r])
                               : ((const ushort_t*)p.src[t])[r];
                break;
            }
            r -= p.n[t];
        }
    }
}

// zero the two h_hat outputs (element offsets [34078720, 34340864)), flag-aware width
__global__ __launch_bounds__(256) void zero_hhat(void* outbase, const int* flagp) {
    long i = 34078720 + (long)blockIdx.x * 256 + threadIdx.x;
    if (*flagp) ((float*)outbase)[i] = 0.f;
    else        ((ushort_t*)outbase)[i] = 0;
}

// ---------------------------------------------------------------------------
// Generic bf16 GEMM (preamble only): out[r, n] = sum_k A(r,k) * W(n,k)
// Block tile 128x128, BK=32, 4 waves (2x2 of 64x64), v_mfma_f32_16x16x32_bf16.
// ---------------------------------------------------------------------------
struct GP {
    const ushort_t* A1; const ushort_t* A2;
    const ushort_t* W1; const ushort_t* W2;
    long lda1, lda2, ldw1, ldw2;
    int K1, wc1, wc2, Nsplit, K, mode;
    const ushort_t* bias; ushort_t* outb; long ldo;          // mode 0
    float* outf; const float* fbias;                         // mode 2
};

__global__ __launch_bounds__(256) void gemm_bt(GP g) {
    __shared__ __attribute__((aligned(16))) ushort_t As[128 * 40];
    __shared__ __attribute__((aligned(16))) ushort_t Bs[128 * 40];
    int tid  = threadIdx.x;
    int lane = tid & 63, wave = tid >> 6;
    int wm = (wave & 1) * 64, wn = (wave >> 1) * 64;
    int ml = lane & 15, quad = lane >> 4;
    long rowA0 = (long)blockIdx.x * 128;
    long rowW0 = (long)blockIdx.y * 128;
    int arow = tid >> 2, acol = (tid & 3) * 8;

    f32x4 acc[4][4];
#pragma unroll
    for (int i = 0; i < 4; i++)
#pragma unroll
        for (int j = 0; j < 4; j++) acc[i][j] = (f32x4){0.f, 0.f, 0.f, 0.f};

    for (int k0 = 0; k0 < g.K; k0 += 32) {
        uint4 av[2], wv[2];
#pragma unroll
        for (int s = 0; s < 2; s++) {
            int r = arow + s * 64;
            int k = k0 + acol;
            const ushort_t* asrc = (k < g.K1)
                ? g.A1 + (rowA0 + r) * g.lda1 + k
                : g.A2 + (rowA0 + r) * g.lda2 + (k - g.K1);
            av[s] = *(const uint4*)asrc;
            long n = rowW0 + r;
            const ushort_t* wsrc = (n < g.Nsplit)
                ? g.W1 + n * g.ldw1 + g.wc1 + k
                : g.W2 + (n - g.Nsplit) * g.ldw2 + g.wc2 + k;
            wv[s] = *(const uint4*)wsrc;
        }
        __syncthreads();
#pragma unroll
        for (int s = 0; s < 2; s++) {
            *(uint4*)&As[(arow + s * 64) * 40 + acol] = av[s];
            *(uint4*)&Bs[(arow + s * 64) * 40 + acol] = wv[s];
        }
        __syncthreads();
        bf16x8 af[4], bfm[4];
#pragma unroll
        for (int i = 0; i < 4; i++)
            af[i] = *(const bf16x8*)&As[(wm + i * 16 + ml) * 40 + quad * 8];
#pragma unroll
        for (int j = 0; j < 4; j++)
            bfm[j] = *(const bf16x8*)&Bs[(wn + j * 16 + ml) * 40 + quad * 8];
#pragma unroll
        for (int i = 0; i < 4; i++)
#pragma unroll
            for (int j = 0; j < 4; j++)
                acc[i][j] = __builtin_amdgcn_mfma_f32_16x16x32_bf16(af[i], bfm[j], acc[i][j], 0, 0, 0);
    }

#pragma unroll
    for (int i = 0; i < 4; i++) {
#pragma unroll
        for (int j = 0; j < 4; j++) {
            long rb = rowA0 + wm + i * 16 + quad * 4;
            long cn = rowW0 + wn + j * 16 + ml;
#pragma unroll
            for (int r = 0; r < 4; r++) {
                float v = acc[i][j][r];
                long rr = rb + r;
                if (g.mode == 0) {
                    if (g.bias) v += bf2f(g.bias[cn]);
                    g.outb[rr * g.ldo + cn] = f2bf(v);
                } else {
                    g.outf[rr * g.ldo + cn] = v + g.fbias[cn];
                }
            }
        }
    }
}

// ---------------------------------------------------------------------------
// Attention: per block b, stage k[b] in LDS, loop t: scores -> softmax -> attended.
// ---------------------------------------------------------------------------
__global__ __launch_bounds__(256) void attn_kernel(const ushort_t* q, const ushort_t* kmat,
                                                   const ushort_t* meta, const int* inp,
                                                   ushort_t* att) {
    int b = blockIdx.x;
    __shared__ __attribute__((aligned(16))) ushort_t klds[L_DIM * 264];
    __shared__ float qlds[256];
    __shared__ float sc[L_DIM];
    __shared__ int msk[L_DIM];
    __shared__ float inv_s;
    int tid = threadIdx.x;

    for (int idx = tid; idx < L_DIM * 32; idx += 256) {
        int r = idx >> 5, c8 = (idx & 31) * 8;
        *(uint4*)&klds[r * 264 + c8] = *(const uint4*)&kmat[((long)b * L_DIM + r) * 256 + c8];
    }
    if (tid < L_DIM) msk[tid] = inp[b * L_DIM + tid];

    for (int t = 0; t < T_DIM; t++) {
        __syncthreads();
        qlds[tid] = bf2f(q[((long)t * B_DIM + b) * 256 + tid]);
        __syncthreads();
        if (tid < 2 * L_DIM) {
            int l = tid >> 1, half = tid & 1;
            const ushort_t* kr = &klds[l * 264 + half * 128];
            const float* qp = &qlds[half * 128];
            float s = 0.f;
            for (int j = 0; j < 128; j++) s += qp[j] * bf2f(kr[j]);
            s += __shfl_xor(s, 1);
            if (half == 0) sc[l] = (msk[l] == 0) ? -1000000000.0f : s * 0.0625f;
        }
        __syncthreads();
        if (tid < 64) {
            float s1 = sc[tid];
            float s2 = (tid + 64 < L_DIM) ? sc[tid + 64] : -1e30f;
            float mx = fmaxf(s1, s2);
            for (int o = 1; o < 64; o <<= 1) mx = fmaxf(mx, __shfl_xor(mx, o));
            float e1 = __expf(s1 - mx);
            float e2 = (tid + 64 < L_DIM) ? __expf(s2 - mx) : 0.f;
            float tot = e1 + e2;
            for (int o = 1; o < 64; o <<= 1) tot += __shfl_xor(tot, o);
            sc[tid] = e1;
            if (tid + 64 < L_DIM) sc[tid + 64] = e2;
            if (tid == 0) inv_s = 1.0f / tot;
        }
        __syncthreads();
        float a = 0.f;
        const ushort_t* mb = &meta[(long)b * L_DIM * 256 + tid];
        for (int l = 0; l < L_DIM; l++) a += sc[l] * bf2f(mb[(long)l * 256]);
        a *= inv_s;
        att[((long)t * B_DIM + b) * 256 + tid] = f2bf(a);
    }
}

// ---------------------------------------------------------------------------
// Precompute C[kind,k] = Wd[kind][k] (512x256) @ Wz[kind][k*256:..] (256x256) -> bf16 (6144 x 256)
// ---------------------------------------------------------------------------
__global__ __launch_bounds__(256) void call_precompute(const ushort_t* Wdh, const ushort_t* Wdx,
                                                       const ushort_t* Wdb, const ushort_t* Wzh,
                                                       const ushort_t* Wzx, const ushort_t* Wzb,
                                                       ushort_t* Call) {
    int bk = blockIdx.x;            // kind*4 + k
    int kind = bk >> 2, kk = bk & 3;
    int h0 = blockIdx.y * 64;
    int m0 = blockIdx.z * 64;
    const ushort_t* Wd = (kind == 0) ? Wdh : ((kind == 1) ? Wdx : Wdb);
    const ushort_t* Wz = (kind == 0) ? Wzh : ((kind == 1) ? Wzx : Wzb);
    __shared__ __attribute__((aligned(16))) ushort_t dt[64 * 72];
    __shared__ __attribute__((aligned(16))) ushort_t zt[64 * 72];
    int tid = threadIdx.x;
    int ty = tid >> 4, tx = tid & 15;
    float acc[4][4] = {};
    for (int z0 = 0; z0 < 256; z0 += 64) {
        __syncthreads();
        for (int idx = tid; idx < 512; idx += 256) {
            int r = idx >> 3, c8 = (idx & 7) * 8;
            *(uint4*)&dt[r * 72 + c8] = *(const uint4*)&Wd[((long)(kk * 512 + h0 + r)) * 256 + z0 + c8];
            *(uint4*)&zt[r * 72 + c8] = *(const uint4*)&Wz[((long)(kk * 256 + z0 + r)) * 256 + m0 + c8];
        }
        __syncthreads();
        for (int z = 0; z < 64; z++) {
            float a[4], bb[4];
#pragma unroll
            for (int i = 0; i < 4; i++) a[i] = bf2f(dt[(ty * 4 + i) * 72 + z]);
#pragma unroll
            for (int j = 0; j < 4; j++) bb[j] = bf2f(zt[z * 72 + tx * 4 + j]);
#pragma unroll
            for (int i = 0; i < 4; i++)
#pragma unroll
                for (int j = 0; j < 4; j++) acc[i][j] += a[i] * bb[j];
        }
    }
#pragma unroll
    for (int i = 0; i < 4; i++)
#pragma unroll
        for (int j = 0; j < 4; j++)
            Call[((long)(kind * 2048 + kk * 512 + h0 + ty * 4 + i)) * 256 + m0 + tx * 4 + j] = f2bf(acc[i][j]);
}

// dbias[n]: kind 0 -> Wdh[k,h,:]·bzh_k ; kind 1 -> Wdx·bzx ; kind 2 -> bdb[k,h]
__global__ __launch_bounds__(256) void dbias_kernel(const ushort_t* Wdh, const ushort_t* Wdx,
                                                    const ushort_t* bzh, const ushort_t* bzx,
                                                    const ushort_t* bdb, float* dbias) {
    int n = blockIdx.x * 256 + threadIdx.x;  // 0..6143
    int kind = n >> 11, kk = (n >> 9) & 3, h = n & 511;
    float s = 0.f;
    if (kind == 2) {
        s = bf2f(bdb[kk * 512 + h]);
    } else {
        const ushort_t* Wd = (kind == 0) ? Wdh : Wdx;
        const ushort_t* bz = (kind == 0) ? bzh : bzx;
        for (int z = 0; z < 256; z++)
            s += bf2f(Wd[((long)(kk * 512 + h)) * 256 + z]) * bf2f(bz[kk * 256 + z]);
    }
    dbias[n] = s;
}

// ---------------------------------------------------------------------------
// Row-local persistent scan: the recurrence has NO cross-b coupling, so each
// block owns 2 batch rows and runs all 128 steps privately. Zero grid syncs.
// Weights streamed global->VGPR as MFMA B-fragments each step (L2-resident,
// ~5.3 MB/CU/step -> per-CU L2 BW bound ~40 us/step).
// Per step: [stage x_t if !full] -> merged GEMM -> sync ->
//           4x gate phase {wh K=512, dh/dx/db K=256 (+wx K=512 if !full),
//                          LN reduce+normalize} -> sync -> LSTM -> sync.
// ---------------------------------------------------------------------------
struct SR {
    const ushort_t* preb;   // [T][512][256] bf16
    const ushort_t* xall;   // [T][512][512] bf16 (canonical x)
    const ushort_t* wxb;    // [T][512][2048] bf16 when full
    const ushort_t* Wm;     // [256][1280]; cols 768..1279 multiply h
    const ushort_t* w_h;    // [2048][512]
    const ushort_t* w_x;    // [2048][512] (used when !full)
    const ushort_t* callb;  // [6144][256]
    const float* dbias;     // [6144]
    const ushort_t* ln_g;   // [2048] (4x512)
    const ushort_t* ln_b;   // [2048]
    void* outbase;
    const int* flagp;
    int full;
};

__global__ __launch_bounds__(512) void scan_rows(SR p) {
    __shared__ __attribute__((aligned(16))) ushort_t h_lds[2][512];
    __shared__ __attribute__((aligned(16))) ushort_t x_lds[2][512];
    __shared__ __attribute__((aligned(16))) ushort_t m_lds[2][256];
    __shared__ float yln[2][4][512];
    __shared__ float red[4][8][4];   // [gate][wave][sum0,ss0,sum1,ss1]

    int tid = threadIdx.x;
    int wave = tid >> 6, lane = tid & 63;
    int quad = lane >> 4, ml = lane & 15;
    long b0 = (long)blockIdx.x * 2;
    int flag = *p.flagp;
    int full = p.full;

    for (int i = tid; i < 1024; i += 512) ((ushort_t*)h_lds)[i] = 0;
    float cr0 = 0.f, cr1 = 0.f;
    __syncthreads();

    for (int t = 0; t < T_DIM; t++) {
        // stage x_t rows (only needed for in-scan wx GEMM)
        if (!full) {
            for (int i = tid; i < 1024; i += 512)
                ((ushort_t*)x_lds)[i] =
                    p.xall[((long)t * 512 + b0 + (i >> 9)) * 512 + (i & 511)];
        }

        // ---- phase 1: merged = relu(pre_t + h @ Wm2^T), 256 cols ----
#pragma unroll
        for (int tt = 0; tt < 2; tt++) {
            int n0 = wave * 32 + tt * 16;
            f32x4 acc = {0.f, 0.f, 0.f, 0.f};
            const ushort_t* wp = p.Wm + (long)(n0 + ml) * 1280 + 768 + quad * 8;
#pragma unroll
            for (int k0 = 0; k0 < 512; k0 += 32) {
                bf16x8 bf = *(const bf16x8*)(wp + k0);
                bf16x8 af = zero8();
                if (ml < 2) af = *(const bf16x8*)&h_lds[ml][k0 + quad * 8];
                acc = __builtin_amdgcn_mfma_f32_16x16x32_bf16(af, bf, acc, 0, 0, 0);
            }
            if (quad == 0) {  // rows 0..3 live in regs 0..3; rows 0,1 valid
                int n = n0 + ml;
                const ushort_t* pr = p.preb + ((long)t * 512 + b0) * 256 + n;
#pragma unroll
                for (int r = 0; r < 2; r++) {
                    float v = acc[r] + bf2f(pr[r * 256]);
                    m_lds[r][n] = f2bf(v > 0.f ? v : 0.f);
                }
            }
        }
        __syncthreads();   // m_lds (and x_lds) ready

        // ---- gate phases ----
#pragma unroll 1
        for (int kk = 0; kk < 4; kk++) {
            float sum0 = 0.f, ss0 = 0.f, sum1 = 0.f, ss1 = 0.f;
#pragma unroll 2
            for (int tt = 0; tt < 4; tt++) {
                int hc = wave * 64 + tt * 16 + ml;   // this lane's col in gate (0..511)
                int n = kk * 512 + hc;
                f32x4 awh = {0.f, 0.f, 0.f, 0.f};
                f32x4 adh = {0.f, 0.f, 0.f, 0.f};
                f32x4 adx = {0.f, 0.f, 0.f, 0.f};
                f32x4 adb = {0.f, 0.f, 0.f, 0.f};
                f32x4 awx = {0.f, 0.f, 0.f, 0.f};
                const ushort_t* whp = p.w_h + (long)n * 512 + quad * 8;
#pragma unroll
                for (int k0 = 0; k0 < 512; k0 += 32) {
                    bf16x8 af = zero8();
                    if (ml < 2) af = *(const bf16x8*)&h_lds[ml][k0 + quad * 8];
                    awh = __builtin_amdgcn_mfma_f32_16x16x32_bf16(
                        af, *(const bf16x8*)(whp + k0), awh, 0, 0, 0);
                }
                if (!full) {
                    const ushort_t* wxp = p.w_x + (long)n * 512 + quad * 8;
#pragma unroll
                    for (int k0 = 0; k0 < 512; k0 += 32) {
                        bf16x8 ax = zero8();
                        if (ml < 2) ax = *(const bf16x8*)&x_lds[ml][k0 + quad * 8];
                        awx = __builtin_amdgcn_mfma_f32_16x16x32_bf16(
                            ax, *(const bf16x8*)(wxp + k0), awx, 0, 0, 0);
                    }
                }
                const ushort_t* c0p = p.callb + (long)n * 256 + quad * 8;
                const ushort_t* c1p = p.callb + (long)(2048 + n) * 256 + quad * 8;
                const ushort_t* c2p = p.callb + (long)(4096 + n) * 256 + quad * 8;
#pragma unroll
                for (int k0 = 0; k0 < 256; k0 += 32) {
                    bf16x8 am = zero8();
                    if (ml < 2) am = *(const bf16x8*)&m_lds[ml][k0 + quad * 8];
                    adh = __builtin_amdgcn_mfma_f32_16x16x32_bf16(
                        am, *(const bf16x8*)(c0p + k0), adh, 0, 0, 0);
                    adx = __builtin_amdgcn_mfma_f32_16x16x32_bf16(
                        am, *(const bf16x8*)(c1p + k0), adx, 0, 0, 0);
                    adb = __builtin_amdgcn_mfma_f32_16x16x32_bf16(
                        am, *(const bf16x8*)(c2p + k0), adb, 0, 0, 0);
                }
                if (quad == 0) {
                    float d0 = p.dbias[n], d1 = p.dbias[2048 + n], d2 = p.dbias[4096 + n];
#pragma unroll
                    for (int r = 0; r < 2; r++) {
                        float wxv = full
                            ? bf2f(p.wxb[((long)t * 512 + b0 + r) * 2048 + n])
                            : awx[r];
                        float v = (adh[r] + d0) * awh[r] + (adx[r] + d1) * wxv + (adb[r] + d2);
                        v = fixf(v);
                        yln[r][kk][hc] = v;
                        if (r == 0) { sum0 += v; ss0 += v * v; }
                        else        { sum1 += v; ss1 += v * v; }
                    }
                }
            }
            // reduce over the 16-lane group (lanes 16..63 carry zeros)
#pragma unroll
            for (int o = 1; o < 16; o <<= 1) {
                sum0 += __shfl_xor(sum0, o); ss0 += __shfl_xor(ss0, o);
                sum1 += __shfl_xor(sum1, o); ss1 += __shfl_xor(ss1, o);
            }
            if (lane == 0) {
                red[kk][wave][0] = sum0; red[kk][wave][1] = ss0;
                red[kk][wave][2] = sum1; red[kk][wave][3] = ss1;
            }
            __syncthreads();
            if (quad == 0) {
                float S0 = 0.f, Q0 = 0.f, S1 = 0.f, Q1 = 0.f;
#pragma unroll
                for (int w2 = 0; w2 < 8; w2++) {
                    S0 += red[kk][w2][0]; Q0 += red[kk][w2][1];
                    S1 += red[kk][w2][2]; Q1 += red[kk][w2][3];
                }
                float mu0 = S0 * (1.f / 512.f), mu1 = S1 * (1.f / 512.f);
                float rs0 = rsqrtf(fmaxf(Q0 * (1.f / 512.f) - mu0 * mu0, 0.f) + 1e-5f);
                float rs1 = rsqrtf(fmaxf(Q1 * (1.f / 512.f) - mu1 * mu1, 0.f) + 1e-5f);
#pragma unroll
                for (int tt = 0; tt < 4; tt++) {
                    int hc = wave * 64 + tt * 16 + ml;
                    float g = bf2f(p.ln_g[kk * 512 + hc]);
                    float bb = bf2f(p.ln_b[kk * 512 + hc]);
                    yln[0][kk][hc] = (yln[0][kk][hc] - mu0) * rs0 * g + bb;
                    yln[1][kk][hc] = (yln[1][kk][hc] - mu1) * rs1 * g + bb;
                }
            }
        }
        __syncthreads();   // yln ready

        // ---- LSTM update + output ----
        {
            int h = tid;   // 0..511
            float i0 = yln[0][0][h], f0 = yln[0][1][h], g0 = yln[0][2][h], o0 = yln[0][3][h];
            float i1 = yln[1][0][h], f1 = yln[1][1][h], g1 = yln[1][2][h], o1 = yln[1][3][h];
            float cn0 = sigmoidf_(f0) * cr0 + sigmoidf_(i0) * tanhf(g0);
            float hn0 = sigmoidf_(o0) * tanhf(cn0);
            float cn1 = sigmoidf_(f1) * cr1 + sigmoidf_(i1) * tanhf(g1);
            float hn1 = sigmoidf_(o1) * tanhf(cn1);
            cr0 = cn0; cr1 = cn1;
            h_lds[0][h] = f2bf(hn0);
            h_lds[1][h] = f2bf(hn1);
            long off_t = (long)t * (B_DIM * H_DIM);
            long ci0 = b0 * 512 + h, ci1 = (b0 + 1) * 512 + h;
            int last = (t == T_DIM - 1);
            if (flag) {
                float* of = (float*)p.outbase;
                of[off_t + ci0] = hn0; of[off_t + ci1] = hn1;
                if (last) {
                    of[33554432 + ci0] = hn0; of[33554432 + ci1] = hn1;
                    of[33816576 + ci0] = cn0; of[33816576 + ci1] = cn1;
                }
            } else {
                ushort_t* ob = (ushort_t*)p.outbase;
                ob[off_t + ci0] = f2bf(hn0); ob[off_t + ci1] = f2bf(hn1);
                if (last) {
                    ob[33554432 + ci0] = f2bf(hn0); ob[33554432 + ci1] = f2bf(hn1);
                    ob[33816576 + ci0] = f2bf(cn0); ob[33816576 + ci1] = f2bf(cn1);
                }
            }
        }
        __syncthreads();   // h_lds ready for next step
    }
}

// ---------------------------------------------------------------------------
extern "C" void kernel_launch(void* const* d_in, const int* in_sizes, int n_in,
                              void* d_out, int out_size, void* d_ws, size_t ws_size,
                              hipStream_t stream) {
    const int* inp = (const int*)d_in[2];

    size_t off = 0;
    char* wsb = (char*)d_ws;
    auto alloc = [&](size_t bytes) -> void* {
        off = (off + 255) & ~(size_t)255;
        void* p = wsb + off;
        off += bytes;
        return p;
    };

    int* flagp = (int*)alloc(256);

    // canonical bf16 copies of all 21 float tensors (skip inp at index 2)
    static const int fidx[21] = {0,1,3,4,5,6,7,8,9,10,11,12,13,14,15,16,17,18,19,20,21};
    IngestP ip{};
    long total = 0;
    ushort_t* canon[21];
    for (int t = 0; t < 21; t++) {
        int src_i = fidx[t];
        int n = in_sizes[src_i];
        canon[t] = (ushort_t*)alloc((size_t)n * 2);
        ip.src[t] = d_in[src_i];
        ip.dst[t] = canon[t];
        ip.n[t] = n;
        total += n;
    }
    ip.total = total;
    ip.flag = flagp;

    const ushort_t* x    = canon[0];
    const ushort_t* meta = canon[1];
    const ushort_t* Wq   = canon[2];
    const ushort_t* bq   = canon[3];
    const ushort_t* Wk   = canon[4];
    const ushort_t* bk   = canon[5];
    const ushort_t* Wm   = canon[6];
    const ushort_t* bm   = canon[7];
    const ushort_t* Wzh  = canon[8];
    const ushort_t* bzh  = canon[9];
    const ushort_t* Wzx  = canon[10];
    const ushort_t* bzx  = canon[11];
    const ushort_t* Wzb  = canon[12];
    const ushort_t* Wdh  = canon[13];
    const ushort_t* Wdx  = canon[14];
    const ushort_t* Wdb  = canon[15];
    const ushort_t* bdb  = canon[16];
    const ushort_t* w_h  = canon[17];
    const ushort_t* w_x  = canon[18];
    const ushort_t* ln_g = canon[19];
    const ushort_t* ln_b = canon[20];

    ushort_t* qb    = (ushort_t*)alloc(33554432);   // 65536 x 256 bf16
    ushort_t* kmb   = (ushort_t*)alloc(26214400);   // 51200 x 256 bf16
    ushort_t* attb  = (ushort_t*)alloc(33554432);   // 65536 x 256 bf16
    ushort_t* preb  = (ushort_t*)alloc(33554432);   // 65536 x 256 bf16
    ushort_t* callb = (ushort_t*)alloc(3145728);    // 6144 x 256 bf16
    float*    dbias = (float*)alloc(24576);         // 6144 f32
    size_t base_end = (off + 255) & ~(size_t)255;
    bool full = (base_end + 268435456ull) <= ws_size;
    ushort_t* wxb = (ushort_t*)alloc(full ? 268435456ull : 256ull);

    // dtype detect + ingest + init
    detect_kernel<<<dim3(1), 256, 0, stream>>>((const ushort_t*)d_in[0], 262144, flagp);
    ingest_all<<<dim3(2048), 256, 0, stream>>>(ip);
    zero_hhat<<<dim3(1024), 256, 0, stream>>>(d_out, flagp);

    const int BIG = 1 << 30;

    // A1: kmat = meta @ Wk^T + bk   (51200 x 256, K=256)
    {
        GP g{};
        g.A1 = meta; g.lda1 = 256; g.K1 = BIG; g.A2 = meta; g.lda2 = 256;
        g.W1 = Wk; g.ldw1 = 256; g.wc1 = 0; g.Nsplit = BIG; g.W2 = Wk; g.ldw2 = 256; g.wc2 = 0;
        g.K = 256; g.mode = 0; g.bias = bk; g.outb = kmb; g.ldo = 256;
        gemm_bt<<<dim3(400, 2), 256, 0, stream>>>(g);
    }
    // A2: q = x @ Wq^T + bq   (65536 x 256, K=512)
    {
        GP g{};
        g.A1 = x; g.lda1 = 512; g.K1 = BIG; g.A2 = x; g.lda2 = 512;
        g.W1 = Wq; g.ldw1 = 512; g.wc1 = 0; g.Nsplit = BIG; g.W2 = Wq; g.ldw2 = 512; g.wc2 = 0;
        g.K = 512; g.mode = 0; g.bias = bq; g.outb = qb; g.ldo = 256;
        gemm_bt<<<dim3(512, 2), 256, 0, stream>>>(g);
    }
    // A3: attention -> attb
    attn_kernel<<<dim3(512), 256, 0, stream>>>(qb, kmb, meta, inp, attb);
    // A4: pre_merged = [x, att] @ Wm[:, :768]^T + bm   (65536 x 256, K=768)
    {
        GP g{};
        g.A1 = x; g.lda1 = 512; g.K1 = 512; g.A2 = attb; g.lda2 = 256;
        g.W1 = Wm; g.ldw1 = 1280; g.wc1 = 0; g.Nsplit = BIG; g.W2 = Wm; g.ldw2 = 1280; g.wc2 = 0;
        g.K = 768; g.mode = 0; g.bias = bm; g.outb = preb; g.ldo = 256;
        gemm_bt<<<dim3(512, 2), 256, 0, stream>>>(g);
    }
    // A5: wx_all = x @ w_x^T   (65536 x 2048, K=512) — only if workspace allows
    if (full) {
        GP g{};
        g.A1 = x; g.lda1 = 512; g.K1 = BIG; g.A2 = x; g.lda2 = 512;
        g.W1 = w_x; g.ldw1 = 512; g.wc1 = 0; g.Nsplit = BIG; g.W2 = w_x; g.ldw2 = 512; g.wc2 = 0;
        g.K = 512; g.mode = 0; g.bias = nullptr; g.outb = wxb; g.ldo = 2048;
        gemm_bt<<<dim3(512, 16), 256, 0, stream>>>(g);
    }
    // P1/P2: combined d-matrices and bias
    call_precompute<<<dim3(12, 8, 4), 256, 0, stream>>>(Wdh, Wdx, Wdb, Wzh, Wzx, Wzb, callb);
    dbias_kernel<<<dim3(24), 256, 0, stream>>>(Wdh, Wdx, bzh, bzx, bdb, dbias);

    // ---- row-local persistent scan: no grid syncs, no per-step launches ----
    SR sr{};
    sr.preb = preb; sr.xall = x; sr.wxb = wxb;
    sr.Wm = Wm; sr.w_h = w_h; sr.w_x = w_x;
    sr.callb = callb; sr.dbias = dbias;
    sr.ln_g = ln_g; sr.ln_b = ln_b;
    sr.outbase = d_out; sr.flagp = flagp;
    sr.full = full ? 1 : 0;
    scan_rows<<<dim3(256), 512, 0, stream>>>(sr);
}

// Round 3
// 22156.406 us; speedup vs baseline: 1.1381x; 1.1381x over previous
//
#include <hip/hip_runtime.h>
#include <hip/hip_bf16.h>

typedef unsigned short ushort_t;
typedef __attribute__((ext_vector_type(8))) short bf16x8;
typedef __attribute__((ext_vector_type(4))) float f32x4;

#define T_DIM 128
#define B_DIM 512
#define DIN 512
#define H_DIM 512
#define DM 256
#define HYP 256
#define L_DIM 100

__device__ __forceinline__ float bf2f(ushort_t u) {
    return __uint_as_float(((unsigned)u) << 16);
}
__device__ __forceinline__ ushort_t f2bf(float f) {
    unsigned u = __float_as_uint(f);
    unsigned r = (u + 0x7fffu + ((u >> 16) & 1u)) >> 16;
    return (ushort_t)r;
}
__device__ __forceinline__ float sigmoidf_(float x) {
    return 1.0f / (1.0f + __expf(-x));
}
// NaN/inf scrub + clamp: keeps garbage-world values finite so failures are diagnosable.
__device__ __forceinline__ float fixf(float v) {
    if (!(v == v)) return 0.f;
    return fminf(fmaxf(v, -65504.f), 65504.f);
}

// ---------------------------------------------------------------------------
// dtype detector: valid bf16 never has exponent 0xFF; f32 read as ushorts does
// (~0.4% of low halves). Single block -> flag: 1 = inputs are f32, 0 = bf16.
// ---------------------------------------------------------------------------
__global__ __launch_bounds__(256) void detect_kernel(const ushort_t* x, int nscan, int* flag) {
    __shared__ int found;
    if (threadIdx.x == 0) found = 0;
    __syncthreads();
    int f = 0;
    for (int i = threadIdx.x; i < nscan; i += 256) {
        unsigned u = x[i];
        if ((u & 0x7F80u) == 0x7F80u) f = 1;
    }
    if (f) atomicOr(&found, 1);
    __syncthreads();
    if (threadIdx.x == 0) *flag = found;
}

// ---------------------------------------------------------------------------
// Ingest: convert all 21 float tensors to canonical bf16 copies in workspace.
// ---------------------------------------------------------------------------
struct IngestP {
    const void* src[21];
    ushort_t* dst[21];
    int n[21];
    long total;
    const int* flag;
};

__global__ __launch_bounds__(256) void ingest_all(IngestP p) {
    int f = *p.flag;
    long idx0 = (long)blockIdx.x * 256 + threadIdx.x;
    long stride = (long)gridDim.x * 256;
    for (long idx = idx0; idx < p.total; idx += stride) {
        long r = idx;
#pragma unroll 1
        for (int t = 0; t < 21; t++) {
            if (r < p.n[t]) {
                p.dst[t][r] = f ? f2bf(((const float*)p.src[t])[r])
                               : ((const ushort_t*)p.src[t])[r];
                break;
            }
            r -= p.n[t];
        }
    }
}

// zero the two h_hat outputs (element offsets [34078720, 34340864)), flag-aware width
__global__ __launch_bounds__(256) void zero_hhat(void* outbase, const int* flagp) {
    long i = 34078720 + (long)blockIdx.x * 256 + threadIdx.x;
    if (*flagp) ((float*)outbase)[i] = 0.f;
    else        ((ushort_t*)outbase)[i] = 0;
}

// ---------------------------------------------------------------------------
// Generic bf16 GEMM (preamble only): out[r, n] = sum_k A(r,k) * W(n,k)
// Block tile 128x128, BK=32, 4 waves (2x2 of 64x64), v_mfma_f32_16x16x32_bf16.
// ---------------------------------------------------------------------------
struct GP {
    const ushort_t* A1; const ushort_t* A2;
    const ushort_t* W1; const ushort_t* W2;
    long lda1, lda2, ldw1, ldw2;
    int K1, wc1, wc2, Nsplit, K, mode;
    const ushort_t* bias; ushort_t* outb; long ldo;          // mode 0
    float* outf; const float* fbias;                         // mode 2
};

__global__ __launch_bounds__(256) void gemm_bt(GP g) {
    __shared__ __attribute__((aligned(16))) ushort_t As[128 * 40];
    __shared__ __attribute__((aligned(16))) ushort_t Bs[128 * 40];
    int tid  = threadIdx.x;
    int lane = tid & 63, wave = tid >> 6;
    int wm = (wave & 1) * 64, wn = (wave >> 1) * 64;
    int ml = lane & 15, quad = lane >> 4;
    long rowA0 = (long)blockIdx.x * 128;
    long rowW0 = (long)blockIdx.y * 128;
    int arow = tid >> 2, acol = (tid & 3) * 8;

    f32x4 acc[4][4];
#pragma unroll
    for (int i = 0; i < 4; i++)
#pragma unroll
        for (int j = 0; j < 4; j++) acc[i][j] = (f32x4){0.f, 0.f, 0.f, 0.f};

    for (int k0 = 0; k0 < g.K; k0 += 32) {
        uint4 av[2], wv[2];
#pragma unroll
        for (int s = 0; s < 2; s++) {
            int r = arow + s * 64;
            int k = k0 + acol;
            const ushort_t* asrc = (k < g.K1)
                ? g.A1 + (rowA0 + r) * g.lda1 + k
                : g.A2 + (rowA0 + r) * g.lda2 + (k - g.K1);
            av[s] = *(const uint4*)asrc;
            long n = rowW0 + r;
            const ushort_t* wsrc = (n < g.Nsplit)
                ? g.W1 + n * g.ldw1 + g.wc1 + k
                : g.W2 + (n - g.Nsplit) * g.ldw2 + g.wc2 + k;
            wv[s] = *(const uint4*)wsrc;
        }
        __syncthreads();
#pragma unroll
        for (int s = 0; s < 2; s++) {
            *(uint4*)&As[(arow + s * 64) * 40 + acol] = av[s];
            *(uint4*)&Bs[(arow + s * 64) * 40 + acol] = wv[s];
        }
        __syncthreads();
        bf16x8 af[4], bfm[4];
#pragma unroll
        for (int i = 0; i < 4; i++)
            af[i] = *(const bf16x8*)&As[(wm + i * 16 + ml) * 40 + quad * 8];
#pragma unroll
        for (int j = 0; j < 4; j++)
            bfm[j] = *(const bf16x8*)&Bs[(wn + j * 16 + ml) * 40 + quad * 8];
#pragma unroll
        for (int i = 0; i < 4; i++)
#pragma unroll
            for (int j = 0; j < 4; j++)
                acc[i][j] = __builtin_amdgcn_mfma_f32_16x16x32_bf16(af[i], bfm[j], acc[i][j], 0, 0, 0);
    }

#pragma unroll
    for (int i = 0; i < 4; i++) {
#pragma unroll
        for (int j = 0; j < 4; j++) {
            long rb = rowA0 + wm + i * 16 + quad * 4;
            long cn = rowW0 + wn + j * 16 + ml;
#pragma unroll
            for (int r = 0; r < 4; r++) {
                float v = acc[i][j][r];
                long rr = rb + r;
                if (g.mode == 0) {
                    if (g.bias) v += bf2f(g.bias[cn]);
                    g.outb[rr * g.ldo + cn] = f2bf(v);
                } else {
                    g.outf[rr * g.ldo + cn] = v + g.fbias[cn];
                }
            }
        }
    }
}

// ---------------------------------------------------------------------------
// Attention: per block b, stage k[b] in LDS, loop t: scores -> softmax -> attended.
// ---------------------------------------------------------------------------
__global__ __launch_bounds__(256) void attn_kernel(const ushort_t* q, const ushort_t* kmat,
                                                   const ushort_t* meta, const int* inp,
                                                   ushort_t* att) {
    int b = blockIdx.x;
    __shared__ __attribute__((aligned(16))) ushort_t klds[L_DIM * 264];
    __shared__ float qlds[256];
    __shared__ float sc[L_DIM];
    __shared__ int msk[L_DIM];
    __shared__ float inv_s;
    int tid = threadIdx.x;

    for (int idx = tid; idx < L_DIM * 32; idx += 256) {
        int r = idx >> 5, c8 = (idx & 31) * 8;
        *(uint4*)&klds[r * 264 + c8] = *(const uint4*)&kmat[((long)b * L_DIM + r) * 256 + c8];
    }
    if (tid < L_DIM) msk[tid] = inp[b * L_DIM + tid];

    for (int t = 0; t < T_DIM; t++) {
        __syncthreads();
        qlds[tid] = bf2f(q[((long)t * B_DIM + b) * 256 + tid]);
        __syncthreads();
        if (tid < 2 * L_DIM) {
            int l = tid >> 1, half = tid & 1;
            const ushort_t* kr = &klds[l * 264 + half * 128];
            const float* qp = &qlds[half * 128];
            float s = 0.f;
            for (int j = 0; j < 128; j++) s += qp[j] * bf2f(kr[j]);
            s += __shfl_xor(s, 1);
            if (half == 0) sc[l] = (msk[l] == 0) ? -1000000000.0f : s * 0.0625f;
        }
        __syncthreads();
        if (tid < 64) {
            float s1 = sc[tid];
            float s2 = (tid + 64 < L_DIM) ? sc[tid + 64] : -1e30f;
            float mx = fmaxf(s1, s2);
            for (int o = 1; o < 64; o <<= 1) mx = fmaxf(mx, __shfl_xor(mx, o));
            float e1 = __expf(s1 - mx);
            float e2 = (tid + 64 < L_DIM) ? __expf(s2 - mx) : 0.f;
            float tot = e1 + e2;
            for (int o = 1; o < 64; o <<= 1) tot += __shfl_xor(tot, o);
            sc[tid] = e1;
            if (tid + 64 < L_DIM) sc[tid + 64] = e2;
            if (tid == 0) inv_s = 1.0f / tot;
        }
        __syncthreads();
        float a = 0.f;
        const ushort_t* mb = &meta[(long)b * L_DIM * 256 + tid];
        for (int l = 0; l < L_DIM; l++) a += sc[l] * bf2f(mb[(long)l * 256]);
        a *= inv_s;
        att[((long)t * B_DIM + b) * 256 + tid] = f2bf(a);
    }
}

// ---------------------------------------------------------------------------
// Precompute C[kind,k] = Wd[kind][k] (512x256) @ Wz[kind][k*256:..] (256x256) -> bf16 (6144 x 256)
// ---------------------------------------------------------------------------
__global__ __launch_bounds__(256) void call_precompute(const ushort_t* Wdh, const ushort_t* Wdx,
                                                       const ushort_t* Wdb, const ushort_t* Wzh,
                                                       const ushort_t* Wzx, const ushort_t* Wzb,
                                                       ushort_t* Call) {
    int bk = blockIdx.x;            // kind*4 + k
    int kind = bk >> 2, kk = bk & 3;
    int h0 = blockIdx.y * 64;
    int m0 = blockIdx.z * 64;
    const ushort_t* Wd = (kind == 0) ? Wdh : ((kind == 1) ? Wdx : Wdb);
    const ushort_t* Wz = (kind == 0) ? Wzh : ((kind == 1) ? Wzx : Wzb);
    __shared__ __attribute__((aligned(16))) ushort_t dt[64 * 72];
    __shared__ __attribute__((aligned(16))) ushort_t zt[64 * 72];
    int tid = threadIdx.x;
    int ty = tid >> 4, tx = tid & 15;
    float acc[4][4] = {};
    for (int z0 = 0; z0 < 256; z0 += 64) {
        __syncthreads();
        for (int idx = tid; idx < 512; idx += 256) {
            int r = idx >> 3, c8 = (idx & 7) * 8;
            *(uint4*)&dt[r * 72 + c8] = *(const uint4*)&Wd[((long)(kk * 512 + h0 + r)) * 256 + z0 + c8];
            *(uint4*)&zt[r * 72 + c8] = *(const uint4*)&Wz[((long)(kk * 256 + z0 + r)) * 256 + m0 + c8];
        }
        __syncthreads();
        for (int z = 0; z < 64; z++) {
            float a[4], bb[4];
#pragma unroll
            for (int i = 0; i < 4; i++) a[i] = bf2f(dt[(ty * 4 + i) * 72 + z]);
#pragma unroll
            for (int j = 0; j < 4; j++) bb[j] = bf2f(zt[z * 72 + tx * 4 + j]);
#pragma unroll
            for (int i = 0; i < 4; i++)
#pragma unroll
                for (int j = 0; j < 4; j++) acc[i][j] += a[i] * bb[j];
        }
    }
#pragma unroll
    for (int i = 0; i < 4; i++)
#pragma unroll
        for (int j = 0; j < 4; j++)
            Call[((long)(kind * 2048 + kk * 512 + h0 + ty * 4 + i)) * 256 + m0 + tx * 4 + j] = f2bf(acc[i][j]);
}

// dbias[n]: kind 0 -> Wdh[k,h,:]·bzh_k ; kind 1 -> Wdx·bzx ; kind 2 -> bdb[k,h]
__global__ __launch_bounds__(256) void dbias_kernel(const ushort_t* Wdh, const ushort_t* Wdx,
                                                    const ushort_t* bzh, const ushort_t* bzx,
                                                    const ushort_t* bdb, float* dbias) {
    int n = blockIdx.x * 256 + threadIdx.x;  // 0..6143
    int kind = n >> 11, kk = (n >> 9) & 3, h = n & 511;
    float s = 0.f;
    if (kind == 2) {
        s = bf2f(bdb[kk * 512 + h]);
    } else {
        const ushort_t* Wd = (kind == 0) ? Wdh : Wdx;
        const ushort_t* bz = (kind == 0) ? bzh : bzx;
        for (int z = 0; z < 256; z++)
            s += bf2f(Wd[((long)(kk * 512 + h)) * 256 + z]) * bf2f(bz[kk * 256 + z]);
    }
    dbias[n] = s;
}

// ---------------------------------------------------------------------------
// Row-local persistent scan v2. Zero grid syncs (recurrence is row-local in b).
// Fix vs v1 (which was latency-bound at VGPR=64, MfmaUtil 0.7%): launch_bounds
// (512,2) -> 256 VGPR budget; per chunk, ALL B-fragments loaded into a register
// array BEFORE the MFMA group (16-24 loads in flight instead of ~2); scalar
// epilogue operands (dbias/wxb/preb) prefetched ahead of the MFMA groups;
// un-predicated A-reads via row-replication h_lds[ml&1].
// Floor: 5.26 MB weights/CU/step at ~135 GB/s per-CU L2 BW ~= 39 us/step.
// ---------------------------------------------------------------------------
struct SR {
    const ushort_t* preb;   // [T][512][256] bf16
    const ushort_t* xall;   // [T][512][512] bf16 (canonical x)
    const ushort_t* wxb;    // [T][512][2048] bf16 when full
    const ushort_t* Wm;     // [256][1280]; cols 768..1279 multiply h
    const ushort_t* w_h;    // [2048][512]
    const ushort_t* w_x;    // [2048][512] (used when !full)
    const ushort_t* callb;  // [6144][256]
    const float* dbias;     // [6144]
    const ushort_t* ln_g;   // [2048] (4x512)
    const ushort_t* ln_b;   // [2048]
    void* outbase;
    const int* flagp;
    int full;
};

#define MFMA16(A, B, C) __builtin_amdgcn_mfma_f32_16x16x32_bf16((A), (B), (C), 0, 0, 0)

__global__ __launch_bounds__(512, 2) void scan_rows(SR p) {
    __shared__ __attribute__((aligned(16))) ushort_t h_lds[2][512];
    __shared__ __attribute__((aligned(16))) ushort_t x_lds[2][512];
    __shared__ __attribute__((aligned(16))) ushort_t m_lds[2][256];
    __shared__ float yln[2][4][512];
    __shared__ float red[4][8][4];   // [gate][wave][sum0,ss0,sum1,ss1]

    int tid = threadIdx.x;
    int wave = tid >> 6, lane = tid & 63;
    int quad = lane >> 4, ml = lane & 15;
    int mlr = ml & 1;                 // A rows replicated: rows {0,1} = batch rows
    long b0 = (long)blockIdx.x * 2;
    int flag = *p.flagp;
    int full = p.full;

    for (int i = tid; i < 1024; i += 512) ((ushort_t*)h_lds)[i] = 0;
    float cr0 = 0.f, cr1 = 0.f;
    __syncthreads();

#pragma unroll 1
    for (int t = 0; t < T_DIM; t++) {
        // stage x_t rows (only needed for in-scan wx GEMM)
        if (!full) {
            for (int i = tid; i < 1024; i += 512)
                ((ushort_t*)x_lds)[i] =
                    p.xall[((long)t * 512 + b0 + (i >> 9)) * 512 + (i & 511)];
        }

        // ---- phase 1: merged = relu(pre_t + h @ Wm2^T), 256 cols ----
        {
            int n_a = wave * 32 + ml, n_b = wave * 32 + 16 + ml;
            float pr0[2], pr1[2];
            if (quad == 0) {
                const ushort_t* pr = p.preb + ((long)t * 512 + b0) * 256;
                pr0[0] = bf2f(pr[n_a]); pr0[1] = bf2f(pr[256 + n_a]);
                pr1[0] = bf2f(pr[n_b]); pr1[1] = bf2f(pr[256 + n_b]);
            }
            bf16x8 wf[32];
#pragma unroll
            for (int tt = 0; tt < 2; tt++) {
                const ushort_t* wp = p.Wm + (long)(wave * 32 + tt * 16 + ml) * 1280 + 768 + quad * 8;
#pragma unroll
                for (int k = 0; k < 16; k++)
                    wf[tt * 16 + k] = *(const bf16x8*)(wp + k * 32);
            }
            f32x4 a0 = {0.f, 0.f, 0.f, 0.f}, a1 = {0.f, 0.f, 0.f, 0.f};
#pragma unroll
            for (int k = 0; k < 16; k++) {
                bf16x8 af = *(const bf16x8*)&h_lds[mlr][k * 32 + quad * 8];
                a0 = MFMA16(af, wf[k], a0);
                a1 = MFMA16(af, wf[16 + k], a1);
            }
            if (quad == 0) {
                float v;
                v = a0[0] + pr0[0]; m_lds[0][n_a] = f2bf(v > 0.f ? v : 0.f);
                v = a0[1] + pr0[1]; m_lds[1][n_a] = f2bf(v > 0.f ? v : 0.f);
                v = a1[0] + pr1[0]; m_lds[0][n_b] = f2bf(v > 0.f ? v : 0.f);
                v = a1[1] + pr1[1]; m_lds[1][n_b] = f2bf(v > 0.f ? v : 0.f);
            }
        }
        __syncthreads();   // m_lds (and x_lds) ready

        // ---- gate phases ----
#pragma unroll 1
        for (int kk = 0; kk < 4; kk++) {
            // prefetch scalar epilogue operands for all 4 tt of this gate
            float d0v[4], d1v[4], d2v[4], wxv0[4], wxv1[4];
            if (quad == 0) {
#pragma unroll
                for (int tt = 0; tt < 4; tt++) {
                    int n = kk * 512 + wave * 64 + tt * 16 + ml;
                    d0v[tt] = p.dbias[n];
                    d1v[tt] = p.dbias[2048 + n];
                    d2v[tt] = p.dbias[4096 + n];
                    if (full) {
                        wxv0[tt] = bf2f(p.wxb[((long)t * 512 + b0) * 2048 + n]);
                        wxv1[tt] = bf2f(p.wxb[((long)t * 512 + b0 + 1) * 2048 + n]);
                    }
                }
            }
            float sum0 = 0.f, ss0 = 0.f, sum1 = 0.f, ss1 = 0.f;
#pragma unroll 1
            for (int tt = 0; tt < 4; tt++) {
                int hc = wave * 64 + tt * 16 + ml;
                int n = kk * 512 + hc;
                f32x4 awh = {0.f, 0.f, 0.f, 0.f};
                f32x4 adh = {0.f, 0.f, 0.f, 0.f};
                f32x4 adx = {0.f, 0.f, 0.f, 0.f};
                f32x4 adb = {0.f, 0.f, 0.f, 0.f};
                f32x4 awx = {0.f, 0.f, 0.f, 0.f};
                const ushort_t* whp = p.w_h + (long)n * 512 + quad * 8;
                if (full) {
                    bf16x8 wf[16];
#pragma unroll
                    for (int k = 0; k < 16; k++)
                        wf[k] = *(const bf16x8*)(whp + k * 32);
#pragma unroll
                    for (int k = 0; k < 16; k++) {
                        bf16x8 af = *(const bf16x8*)&h_lds[mlr][k * 32 + quad * 8];
                        awh = MFMA16(af, wf[k], awh);
                    }
                } else {
                    bf16x8 wf[16], xf[16];
                    const ushort_t* wxp = p.w_x + (long)n * 512 + quad * 8;
#pragma unroll
                    for (int k = 0; k < 16; k++) {
                        wf[k] = *(const bf16x8*)(whp + k * 32);
                        xf[k] = *(const bf16x8*)(wxp + k * 32);
                    }
#pragma unroll
                    for (int k = 0; k < 16; k++) {
                        bf16x8 af = *(const bf16x8*)&h_lds[mlr][k * 32 + quad * 8];
                        bf16x8 ax = *(const bf16x8*)&x_lds[mlr][k * 32 + quad * 8];
                        awh = MFMA16(af, wf[k], awh);
                        awx = MFMA16(ax, xf[k], awx);
                    }
                }
                {
                    const ushort_t* c0p = p.callb + (long)n * 256 + quad * 8;
                    const ushort_t* c1p = c0p + (long)2048 * 256;
                    const ushort_t* c2p = c0p + (long)4096 * 256;
                    bf16x8 cf[24];
#pragma unroll
                    for (int k = 0; k < 8; k++) {
                        cf[k]      = *(const bf16x8*)(c0p + k * 32);
                        cf[8 + k]  = *(const bf16x8*)(c1p + k * 32);
                        cf[16 + k] = *(const bf16x8*)(c2p + k * 32);
                    }
#pragma unroll
                    for (int k = 0; k < 8; k++) {
                        bf16x8 am = *(const bf16x8*)&m_lds[mlr][k * 32 + quad * 8];
                        adh = MFMA16(am, cf[k], adh);
                        adx = MFMA16(am, cf[8 + k], adx);
                        adb = MFMA16(am, cf[16 + k], adb);
                    }
                }
                if (quad == 0) {
                    float w0 = full ? wxv0[tt] : awx[0];
                    float w1 = full ? wxv1[tt] : awx[1];
                    float v0 = (adh[0] + d0v[tt]) * awh[0] + (adx[0] + d1v[tt]) * w0
                             + (adb[0] + d2v[tt]);
                    v0 = fixf(v0);
                    yln[0][kk][hc] = v0;
                    sum0 += v0; ss0 += v0 * v0;
                    float v1 = (adh[1] + d0v[tt]) * awh[1] + (adx[1] + d1v[tt]) * w1
                             + (adb[1] + d2v[tt]);
                    v1 = fixf(v1);
                    yln[1][kk][hc] = v1;
                    sum1 += v1; ss1 += v1 * v1;
                }
            }
            // reduce over the 16-lane group (lanes with quad!=0 carry zeros)
#pragma unroll
            for (int o = 1; o < 16; o <<= 1) {
                sum0 += __shfl_xor(sum0, o); ss0 += __shfl_xor(ss0, o);
                sum1 += __shfl_xor(sum1, o); ss1 += __shfl_xor(ss1, o);
            }
            if (lane == 0) {
                red[kk][wave][0] = sum0; red[kk][wave][1] = ss0;
                red[kk][wave][2] = sum1; red[kk][wave][3] = ss1;
            }
            __syncthreads();
            if (quad == 0) {
                float S0 = 0.f, Q0 = 0.f, S1 = 0.f, Q1 = 0.f;
#pragma unroll
                for (int w2 = 0; w2 < 8; w2++) {
                    S0 += red[kk][w2][0]; Q0 += red[kk][w2][1];
                    S1 += red[kk][w2][2]; Q1 += red[kk][w2][3];
                }
                float mu0 = S0 * (1.f / 512.f), mu1 = S1 * (1.f / 512.f);
                float rs0 = rsqrtf(fmaxf(Q0 * (1.f / 512.f) - mu0 * mu0, 0.f) + 1e-5f);
                float rs1 = rsqrtf(fmaxf(Q1 * (1.f / 512.f) - mu1 * mu1, 0.f) + 1e-5f);
#pragma unroll
                for (int tt = 0; tt < 4; tt++) {
                    int hc = wave * 64 + tt * 16 + ml;
                    float g = bf2f(p.ln_g[kk * 512 + hc]);
                    float bb = bf2f(p.ln_b[kk * 512 + hc]);
                    yln[0][kk][hc] = (yln[0][kk][hc] - mu0) * rs0 * g + bb;
                    yln[1][kk][hc] = (yln[1][kk][hc] - mu1) * rs1 * g + bb;
                }
            }
        }
        __syncthreads();   // yln ready

        // ---- LSTM update + output ----
        {
            int h = tid;   // 0..511
            float i0 = yln[0][0][h], f0 = yln[0][1][h], g0 = yln[0][2][h], o0 = yln[0][3][h];
            float i1 = yln[1][0][h], f1 = yln[1][1][h], g1 = yln[1][2][h], o1 = yln[1][3][h];
            float cn0 = sigmoidf_(f0) * cr0 + sigmoidf_(i0) * tanhf(g0);
            float hn0 = sigmoidf_(o0) * tanhf(cn0);
            float cn1 = sigmoidf_(f1) * cr1 + sigmoidf_(i1) * tanhf(g1);
            float hn1 = sigmoidf_(o1) * tanhf(cn1);
            cr0 = cn0; cr1 = cn1;
            h_lds[0][h] = f2bf(hn0);
            h_lds[1][h] = f2bf(hn1);
            long off_t = (long)t * (B_DIM * H_DIM);
            long ci0 = b0 * 512 + h, ci1 = (b0 + 1) * 512 + h;
            int last = (t == T_DIM - 1);
            if (flag) {
                float* of = (float*)p.outbase;
                of[off_t + ci0] = hn0; of[off_t + ci1] = hn1;
                if (last) {
                    of[33554432 + ci0] = hn0; of[33554432 + ci1] = hn1;
                    of[33816576 + ci0] = cn0; of[33816576 + ci1] = cn1;
                }
            } else {
                ushort_t* ob = (ushort_t*)p.outbase;
                ob[off_t + ci0] = f2bf(hn0); ob[off_t + ci1] = f2bf(hn1);
                if (last) {
                    ob[33554432 + ci0] = f2bf(hn0); ob[33554432 + ci1] = f2bf(hn1);
                    ob[33816576 + ci0] = f2bf(cn0); ob[33816576 + ci1] = f2bf(cn1);
                }
            }
        }
        __syncthreads();   // h_lds ready for next step
    }
}

// ---------------------------------------------------------------------------
extern "C" void kernel_launch(void* const* d_in, const int* in_sizes, int n_in,
                              void* d_out, int out_size, void* d_ws, size_t ws_size,
                              hipStream_t stream) {
    const int* inp = (const int*)d_in[2];

    size_t off = 0;
    char* wsb = (char*)d_ws;
    auto alloc = [&](size_t bytes) -> void* {
        off = (off + 255) & ~(size_t)255;
        void* p = wsb + off;
        off += bytes;
        return p;
    };

    int* flagp = (int*)alloc(256);

    // canonical bf16 copies of all 21 float tensors (skip inp at index 2)
    static const int fidx[21] = {0,1,3,4,5,6,7,8,9,10,11,12,13,14,15,16,17,18,19,20,21};
    IngestP ip{};
    long total = 0;
    ushort_t* canon[21];
    for (int t = 0; t < 21; t++) {
        int src_i = fidx[t];
        int n = in_sizes[src_i];
        canon[t] = (ushort_t*)alloc((size_t)n * 2);
        ip.src[t] = d_in[src_i];
        ip.dst[t] = canon[t];
        ip.n[t] = n;
        total += n;
    }
    ip.total = total;
    ip.flag = flagp;

    const ushort_t* x    = canon[0];
    const ushort_t* meta = canon[1];
    const ushort_t* Wq   = canon[2];
    const ushort_t* bq   = canon[3];
    const ushort_t* Wk   = canon[4];
    const ushort_t* bk   = canon[5];
    const ushort_t* Wm   = canon[6];
    const ushort_t* bm   = canon[7];
    const ushort_t* Wzh  = canon[8];
    const ushort_t* bzh  = canon[9];
    const ushort_t* Wzx  = canon[10];
    const ushort_t* bzx  = canon[11];
    const ushort_t* Wzb  = canon[12];
    const ushort_t* Wdh  = canon[13];
    const ushort_t* Wdx  = canon[14];
    const ushort_t* Wdb  = canon[15];
    const ushort_t* bdb  = canon[16];
    const ushort_t* w_h  = canon[17];
    const ushort_t* w_x  = canon[18];
    const ushort_t* ln_g = canon[19];
    const ushort_t* ln_b = canon[20];

    ushort_t* qb    = (ushort_t*)alloc(33554432);   // 65536 x 256 bf16
    ushort_t* kmb   = (ushort_t*)alloc(26214400);   // 51200 x 256 bf16
    ushort_t* attb  = (ushort_t*)alloc(33554432);   // 65536 x 256 bf16
    ushort_t* preb  = (ushort_t*)alloc(33554432);   // 65536 x 256 bf16
    ushort_t* callb = (ushort_t*)alloc(3145728);    // 6144 x 256 bf16
    float*    dbias = (float*)alloc(24576);         // 6144 f32
    size_t base_end = (off + 255) & ~(size_t)255;
    bool full = (base_end + 268435456ull) <= ws_size;
    ushort_t* wxb = (ushort_t*)alloc(full ? 268435456ull : 256ull);

    // dtype detect + ingest + init
    detect_kernel<<<dim3(1), 256, 0, stream>>>((const ushort_t*)d_in[0], 262144, flagp);
    ingest_all<<<dim3(2048), 256, 0, stream>>>(ip);
    zero_hhat<<<dim3(1024), 256, 0, stream>>>(d_out, flagp);

    const int BIG = 1 << 30;

    // A1: kmat = meta @ Wk^T + bk   (51200 x 256, K=256)
    {
        GP g{};
        g.A1 = meta; g.lda1 = 256; g.K1 = BIG; g.A2 = meta; g.lda2 = 256;
        g.W1 = Wk; g.ldw1 = 256; g.wc1 = 0; g.Nsplit = BIG; g.W2 = Wk; g.ldw2 = 256; g.wc2 = 0;
        g.K = 256; g.mode = 0; g.bias = bk; g.outb = kmb; g.ldo = 256;
        gemm_bt<<<dim3(400, 2), 256, 0, stream>>>(g);
    }
    // A2: q = x @ Wq^T + bq   (65536 x 256, K=512)
    {
        GP g{};
        g.A1 = x; g.lda1 = 512; g.K1 = BIG; g.A2 = x; g.lda2 = 512;
        g.W1 = Wq; g.ldw1 = 512; g.wc1 = 0; g.Nsplit = BIG; g.W2 = Wq; g.ldw2 = 512; g.wc2 = 0;
        g.K = 512; g.mode = 0; g.bias = bq; g.outb = qb; g.ldo = 256;
        gemm_bt<<<dim3(512, 2), 256, 0, stream>>>(g);
    }
    // A3: attention -> attb
    attn_kernel<<<dim3(512), 256, 0, stream>>>(qb, kmb, meta, inp, attb);
    // A4: pre_merged = [x, att] @ Wm[:, :768]^T + bm   (65536 x 256, K=768)
    {
        GP g{};
        g.A1 = x; g.lda1 = 512; g.K1 = 512; g.A2 = attb; g.lda2 = 256;
        g.W1 = Wm; g.ldw1 = 1280; g.wc1 = 0; g.Nsplit = BIG; g.W2 = Wm; g.ldw2 = 1280; g.wc2 = 0;
        g.K = 768; g.mode = 0; g.bias = bm; g.outb = preb; g.ldo = 256;
        gemm_bt<<<dim3(512, 2), 256, 0, stream>>>(g);
    }
    // A5: wx_all = x @ w_x^T   (65536 x 2048, K=512) — only if workspace allows
    if (full) {
        GP g{};
        g.A1 = x; g.lda1 = 512; g.K1 = BIG; g.A2 = x; g.lda2 = 512;
        g.W1 = w_x; g.ldw1 = 512; g.wc1 = 0; g.Nsplit = BIG; g.W2 = w_x; g.ldw2 = 512; g.wc2 = 0;
        g.K = 512; g.mode = 0; g.bias = nullptr; g.outb = wxb; g.ldo = 2048;
        gemm_bt<<<dim3(512, 16), 256, 0, stream>>>(g);
    }
    // P1/P2: combined d-matrices and bias
    call_precompute<<<dim3(12, 8, 4), 256, 0, stream>>>(Wdh, Wdx, Wdb, Wzh, Wzx, Wzb, callb);
    dbias_kernel<<<dim3(24), 256, 0, stream>>>(Wdh, Wdx, bzh, bzx, bdb, dbias);

    // ---- row-local persistent scan: no grid syncs, no per-step launches ----
    SR sr{};
    sr.preb = preb; sr.xall = x; sr.wxb = wxb;
    sr.Wm = Wm; sr.w_h = w_h; sr.w_x = w_x;
    sr.callb = callb; sr.dbias = dbias;
    sr.ln_g = ln_g; sr.ln_b = ln_b;
    sr.outbase = d_out; sr.flagp = flagp;
    sr.full = full ? 1 : 0;
    scan_rows<<<dim3(256), 512, 0, stream>>>(sr);
}